// Round 10
// baseline (152.200 us; speedup 1.0000x reference)
//
#include <hip/hip_runtime.h>
#include <math.h>

#define NL 5
#define KM 5
#define MF 50
#define BATCH_ 131072
#define XROW (NL + 2*MF)      /* 105 */
#define SROW (KM*(2*NL+1))    /* 55  */
#define LOG2PI_F 1.8378770664093453f

#define BPB 64                    /* batches per block, 2 lanes per batch */
#define TPB 128
#define NB_FUSED (BATCH_/BPB)     /* 2048 */
#define NB_MONO  (BATCH_/256)     /* 512  */

typedef float v2f __attribute__((ext_vector_type(2)));

__device__ __forceinline__ float rcpf_(float x)  { return __builtin_amdgcn_rcpf(x); }
__device__ __forceinline__ float sqrtf_(float x) { return __builtin_amdgcn_sqrtf(x); }
__device__ __forceinline__ float exp_(float x)   { return __expf(x); }
__device__ __forceinline__ float log_(float x)   { return __logf(x); }

// ndtr via A&S 7.1.26 erf (|eps| <= 1.5e-7)
__device__ __forceinline__ float ndtr_f(float x) {
    float z = fabsf(x) * 0.70710678f;
    float t = rcpf_(fmaf(0.3275911f, z, 1.0f));
    float poly = t*(0.254829592f + t*(-0.284496736f + t*(1.421413741f +
                 t*(-1.453152027f + t*1.061405429f))));
    float h = 0.5f * poly * exp_(-z*z);
    return x >= 0.0f ? 1.0f - h : h;
}

// ndtri via Giles' erfinv. Caller overrides exact endpoints.
__device__ __forceinline__ float ndtri_f(float p) {
    float x = fmaf(2.0f, p, -1.0f);
    float w = -log_((1.0f - x) * (1.0f + x));
    float wc = w - 2.5f;
    float pc =            2.81022636e-08f;
    pc = fmaf(pc, wc,     3.43273939e-07f);
    pc = fmaf(pc, wc,    -3.5233877e-06f);
    pc = fmaf(pc, wc,    -4.39150654e-06f);
    pc = fmaf(pc, wc,     0.00021858087f);
    pc = fmaf(pc, wc,    -0.00125372503f);
    pc = fmaf(pc, wc,    -0.00417768164f);
    pc = fmaf(pc, wc,     0.246640727f);
    pc = fmaf(pc, wc,     1.50140941f);
    float wt = sqrtf_(w) - 3.0f;
    float pt =           -0.000200214257f;
    pt = fmaf(pt, wt,     0.000100950558f);
    pt = fmaf(pt, wt,     0.00134934322f);
    pt = fmaf(pt, wt,    -0.00367342844f);
    pt = fmaf(pt, wt,     0.00573950773f);
    pt = fmaf(pt, wt,    -0.0076224613f);
    pt = fmaf(pt, wt,     0.00943887047f);
    pt = fmaf(pt, wt,     1.00167406f);
    pt = fmaf(pt, wt,     2.83297682f);
    float r = (w < 5.0f) ? pc : pt;
    return 1.41421356f * r * x;
}

// octant-reduced atan2, degree-11 odd minimax (~1e-6 rad)
__device__ __forceinline__ float atan2_f(float y, float x) {
    float ax = fabsf(x), ay = fabsf(y);
    float mx = fmaxf(ax, ay), mn = fminf(ax, ay);
    float a = mn * rcpf_(mx);
    float s = a * a;
    float r =            -0.01172120f;
    r = fmaf(r, s,        0.05265332f);
    r = fmaf(r, s,       -0.11643287f);
    r = fmaf(r, s,        0.19354346f);
    r = fmaf(r, s,       -0.33262347f);
    r = fmaf(r, s,        0.99997726f);
    r = r * a;
    r = (ay > ax)   ? (1.5707964f - r) : r;
    r = (x < 0.0f)  ? (3.1415927f - r) : r;
    return (y < 0.0f) ? -r : r;
}

// ---------- forward model, one (batch,freq) ----------
// Z' = Zj*(U-W)/(U+W), U=Zj+Z, W=ej*(Zj-Z), Zj=wj(1+i): one rcp per layer.
// c5 = 5.1026102 - ex;  log10(absZ2/(MU*w)) = 0.4342945*ln(absZ2) + c5
__device__ __forceinline__ float fwd_eval(float c5, float sw, float oA, float oP,
                                          const float pr[9])
{
    float z0 = sw * pr[0];
    v2f Z = {z0, z0};
    #pragma unroll
    for (int j = NL-2; j >= 0; --j) {
        float wj = sw * pr[5+j];
        float t  = sw * pr[1+j];          // <= ~0.112
        float t2 = t * t, t3 = t2 * t;
        float ejR = (1.0f - t) + t3 * fmaf(-0.16666667f, t, 0.33333334f);
        float ejC = fmaf(t3, -0.33333334f, t2) - t;
        v2f V = (v2f){wj, wj} - Z;
        v2f U = (v2f){wj, wj} + Z;
        v2f Vs = (v2f){-V.y, V.x};
        v2f W = ejR * V + ejC * Vs;
        v2f Nv = U - W;
        v2f D  = U + W;
        float invd = rcpf_(fmaf(D.x, D.x, D.y*D.y));
        float PR = fmaf(Nv.x, D.x,  Nv.y*D.y);
        float PC = fmaf(Nv.y, D.x, -Nv.x*D.y);
        float g  = wj * invd;
        Z = (v2f){g * (PR - PC), g * (PR + PC)};
    }
    float absZ2 = fmaf(Z.x, Z.x, Z.y*Z.y);
    float aRes  = fmaf(0.43429448f, log_(absZ2), c5);
    float ph    = atan2_f(Z.y, Z.x);
    float prod = aRes * ph;
    float ap   = fabsf(prod);
    float invp = rcpf_(ap);                       // 1/(|aRes||ph|)
    float vA = (aRes - oA) * (33.333332f * fabsf(ph)   * invp);
    float vP = (ph   - oP) * (33.333332f * fabsf(aRes) * invp);
    // constants: -ln(9e-4) - LOG2PI = 5.1752387
    return fmaf(-0.5f, vA*vA, fmaf(-0.5f, vP*vP, 5.1752387f - log_(ap)));
}

// ---------------- fused kernel ----------------
// prep: 2 lanes/batch, 3 layer-reps per lane (layer = i + 2r)
// fwd : 2 lanes/batch, lane i -> contiguous m in [25i, 25i+25): exactly 25 each
__global__ void __launch_bounds__(TPB, 8) k_bnn(
    const float* __restrict__ x, const float* __restrict__ s,
    const float* __restrict__ u_cat, const float* __restrict__ u_trunc,
    float* __restrict__ p_ll, float* __restrict__ p_lq)
{
    __shared__ float lds_pr[BPB][13];     // 13: coprime with 32 banks
    __shared__ float red0[2], red1[2];

    unsigned tid = threadIdx.x;
    unsigned bl = tid >> 1;               // 0..63
    unsigned i  = tid & 1;
    unsigned b  = blockIdx.x * BPB + bl;
    const float* srow = s + (size_t)b * SROW;
    float lqv = 0.0f;

    // --- batch-common (duplicated 2x per batch) ---
    float pro[KM];
    float sqsum = 0.0f;
    #pragma unroll
    for (int k = 0; k < KM; ++k) {
        float v = srow[k*11 + 10];
        pro[k] = v * v;
        sqsum += pro[k];
    }
    float isq = rcpf_(sqsum);
    #pragma unroll
    for (int k = 0; k < KM; ++k) pro[k] *= isq;
    float u = u_cat[b];
    float cum = 0.0f; int cnt = 0;
    #pragma unroll
    for (int k = 0; k < KM; ++k) { cum += pro[k]; if (u > cum) ++cnt; }
    int comp = cnt < KM-1 ? cnt : KM-1;

    // --- per-layer cells: rep r -> layer i + 2r (lane1/r2 = layer 5, inactive)
    float cacc[KM];
    #pragma unroll
    for (int k = 0; k < KM; ++k) cacc[k] = 0.0f;

    #pragma unroll
    for (int r = 0; r < 3; ++r) {
        unsigned layer = i + 2u*r;
        bool active = (layer < NL);
        unsigned ll_ = active ? layer : i;
        float lc[KM], sg[KM];
        #pragma unroll
        for (int k = 0; k < KM; ++k) {
            lc[k] = 4.0f * rcpf_(1.0f + exp_(-srow[k*11 + ll_]));
            float sv = srow[k*11 + 5 + ll_];
            sg[k] = fmaxf(sv, 0.0f) + log_(1.0f + exp_(-fabsf(sv)));
        }
        float ls = lc[0], ss = sg[0];
        #pragma unroll
        for (int k = 1; k < KM; ++k) {
            bool sel = (k == comp);
            ls = sel ? lc[k] : ls;
            ss = sel ? sg[k] : ss;
        }
        float invss = rcpf_(ss);
        float a  = (0.1f - ls) * invss;
        float bb = (3.9f - ls) * invss;
        float Fa = ndtr_f(a), Fb = ndtr_f(bb);
        float p  = Fa + u_trunc[(size_t)b*NL + ll_] * (Fb - Fa);
        p = fminf(fmaxf(p, 0.0f), 1.0f);
        float z = ndtri_f(p);
        if (p <= 0.0f) z = -INFINITY;
        if (p >= 1.0f) z =  INFINITY;
        float smp = fminf(fmaxf(fmaf(ss, z, ls), 0.1f), 3.9f);

        #pragma unroll
        for (int k = 0; k < KM; ++k) {
            float invs = rcpf_(sg[k]);
            float zc = (smp - lc[k]) * invs;
            float a_ = (-lc[k]) * invs;
            float b_ = (4.0f - lc[k]) * invs;
            float Z  = ndtr_f(b_) - ndtr_f(a_);   // >= ~0.29
            float v  = fmaf(-0.5f, zc*zc, -0.5f*LOG2PI_F) - log_(sg[k] * Z);
            cacc[k] += active ? v : 0.0f;
        }
        const float SQM = 7.9267442e-04f;     // sqrt(MU/2)
        const float HLN10 = 1.1512925f;       // 0.5*ln(10)
        float em  = exp_(-HLN10 * smp);       // 10^(-smp/2)
        float emi = SQM * rcpf_(em);          // SQM*10^(+smp/2)
        if (r < 2) {                          // layers 0..3
            float th = x[(size_t)b*XROW + layer];
            lds_pr[bl][1+layer] = 2.0f * th * SQM * em;
            lds_pr[bl][5+layer] = emi;
        } else if (active) {                  // lane 0, layer 4
            lds_pr[bl][0] = emi;
        }
    }
    #pragma unroll
    for (int k = 0; k < KM; ++k)
        cacc[k] += __shfl_xor(cacc[k], 1, 2);
    {
        float mx = -INFINITY;
        float av[KM];
        #pragma unroll
        for (int k = 0; k < KM; ++k) { av[k] = log_(pro[k]) + cacc[k]; mx = fmaxf(mx, av[k]); }
        float se = 0.0f;
        #pragma unroll
        for (int k = 0; k < KM; ++k) se += exp_(av[k] - mx);
        if (i == 0) lqv = mx + log_(se);
    }
    __syncthreads();

    // --- forward phase: lane i -> m in [25i, 25i+25), exactly 25 evals ---
    float pr[9];
    #pragma unroll
    for (int q = 0; q < 9; ++q) pr[q] = lds_pr[bl][q];
    const float* oArow = x + (size_t)b * XROW + NL + 25u*i;
    const float* oProw = oArow + MF;

    float ex = fmaf((float)(25u*i), 0.10204082f, -2.0f);
    float c5 = 5.1026102f - ex;
    float sw = 2.5066283f * exp_(1.1512925f * ex);
    float ll = 0.0f;
    #pragma unroll
    for (int k = 0; k < 25; ++k) {
        ll += fwd_eval(c5, sw, oArow[k], oProw[k], pr);
        c5 -= 0.10204082f;                // m += 1
        sw *= 1.1246574f;                 // 10^(0.10204082/2)
    }

    #pragma unroll
    for (int off = 32; off > 0; off >>= 1) {
        ll  += __shfl_down(ll,  off, 64);
        lqv += __shfl_down(lqv, off, 64);
    }
    if ((tid & 63) == 0) {
        red0[tid >> 6] = ll;
        red1[tid >> 6] = lqv;
    }
    __syncthreads();
    if (tid == 0) {
        p_ll[blockIdx.x] = red0[0] + red0[1];
        p_lq[blockIdx.x] = red1[0] + red1[1];
    }
}

// ---------------- fallback (tiny ws): serial per-batch ----------------
__global__ void __launch_bounds__(256) k_mono(
    const float* __restrict__ x, const float* __restrict__ s,
    const float* __restrict__ u_cat, const float* __restrict__ u_trunc,
    float* __restrict__ p_ll, float* __restrict__ p_lq)
{
    int b = blockIdx.x * 256 + threadIdx.x;
    const float* srow = s + (size_t)b * SROW;
    float loc[KM][NL], sig[KM][NL], pro[KM];
    float sqsum = 0.0f;
    #pragma unroll
    for (int k = 0; k < KM; ++k) { float v = srow[k*11+10]; pro[k] = v*v; sqsum += pro[k]; }
    float isq = rcpf_(sqsum);
    #pragma unroll
    for (int k = 0; k < KM; ++k) pro[k] *= isq;
    #pragma unroll
    for (int k = 0; k < KM; ++k)
        #pragma unroll
        for (int i = 0; i < NL; ++i) {
            loc[k][i] = 4.0f * rcpf_(1.0f + exp_(-srow[k*11+i]));
            float v = srow[k*11+5+i];
            sig[k][i] = fmaxf(v, 0.0f) + log_(1.0f + exp_(-fabsf(v)));
        }
    float u = u_cat[b];
    float cum = 0.0f; int cnt = 0;
    #pragma unroll
    for (int k = 0; k < KM; ++k) { cum += pro[k]; if (u > cum) ++cnt; }
    int comp = cnt < KM-1 ? cnt : KM-1;
    float ls[NL], ss[NL];
    #pragma unroll
    for (int i = 0; i < NL; ++i) { ls[i] = loc[0][i]; ss[i] = sig[0][i]; }
    #pragma unroll
    for (int k = 1; k < KM; ++k) {
        bool sel = (k == comp);
        #pragma unroll
        for (int i = 0; i < NL; ++i) {
            ls[i] = sel ? loc[k][i] : ls[i];
            ss[i] = sel ? sig[k][i] : ss[i];
        }
    }
    float smp[NL];
    #pragma unroll
    for (int i = 0; i < NL; ++i) {
        float invss = rcpf_(ss[i]);
        float a  = (0.1f - ls[i]) * invss;
        float bb = (3.9f - ls[i]) * invss;
        float Fa = ndtr_f(a), Fb = ndtr_f(bb);
        float p  = Fa + u_trunc[(size_t)b*NL + i] * (Fb - Fa);
        p = fminf(fmaxf(p, 0.0f), 1.0f);
        float z  = ndtri_f(p);
        if (p <= 0.0f) z = -INFINITY;
        if (p >= 1.0f) z =  INFINITY;
        smp[i] = fminf(fmaxf(fmaf(ss[i], z, ls[i]), 0.1f), 3.9f);
    }
    float vals[KM]; float mx = -INFINITY;
    #pragma unroll
    for (int k = 0; k < KM; ++k) {
        float av = log_(pro[k]);
        #pragma unroll
        for (int i = 0; i < NL; ++i) {
            float l = loc[k][i], sgv = sig[k][i];
            float invs = rcpf_(sgv);
            float zc = (smp[i] - l) * invs;
            float a_ = (-l) * invs;
            float b_ = (4.0f - l) * invs;
            float Z  = ndtr_f(b_) - ndtr_f(a_);
            av += fmaf(-0.5f, zc*zc, -0.5f*LOG2PI_F) - log_(sgv * Z);
        }
        vals[k] = av; mx = fmaxf(mx, av);
    }
    float se = 0.0f;
    #pragma unroll
    for (int k = 0; k < KM; ++k) se += exp_(vals[k] - mx);
    float lq = mx + log_(se);
    const float SQM = 7.9267442e-04f;
    const float HLN10 = 1.1512925f;
    float pr[9];
    pr[0] = SQM * exp_(HLN10 * smp[NL-1]);
    #pragma unroll
    for (int j = 0; j < NL-1; ++j) {
        float em = exp_(-HLN10 * smp[j]);
        float th = x[(size_t)b*XROW + j];
        pr[1+j] = 2.0f * th * SQM * em;
        pr[5+j] = SQM * rcpf_(em);
    }
    const float* xrow = x + (size_t)b * XROW;
    float ll = 0.0f;
    for (int m = 0; m < MF; ++m) {
        float ex = fmaf((float)m, 0.10204082f, -2.0f);
        float sw = 2.5066283f * exp_(1.1512925f * ex);
        ll += fwd_eval(5.1026102f - ex, sw, xrow[NL + m], xrow[NL + MF + m], pr);
    }

    __shared__ float red0[4], red1[4];
    #pragma unroll
    for (int off = 32; off > 0; off >>= 1) {
        ll += __shfl_down(ll, off, 64);
        lq += __shfl_down(lq, off, 64);
    }
    if ((threadIdx.x & 63) == 0) { red0[threadIdx.x>>6] = ll; red1[threadIdx.x>>6] = lq; }
    __syncthreads();
    if (threadIdx.x == 0) {
        p_ll[blockIdx.x] = red0[0]+red0[1]+red0[2]+red0[3];
        p_lq[blockIdx.x] = red1[0]+red1[1]+red1[2]+red1[3];
    }
}

// ---------------- final reduction ----------------
__global__ void __launch_bounds__(256) k_fin(
    const float* __restrict__ p_ll, const float* __restrict__ p_lq, int n,
    float* __restrict__ out)
{
    int tid = threadIdx.x;
    double a1 = 0.0, a0 = 0.0;
    for (int j = tid; j < n; j += 256) {
        a1 += (double)p_ll[j];
        a0 += (double)p_lq[j];
    }
    #pragma unroll
    for (int off = 32; off > 0; off >>= 1) {
        a0 += __shfl_down(a0, off, 64);
        a1 += __shfl_down(a1, off, 64);
    }
    __shared__ double r0[4], r1[4];
    if ((tid & 63) == 0) { r0[tid >> 6] = a0; r1[tid >> 6] = a1; }
    __syncthreads();
    if (tid == 0) {
        double A0 = r0[0]+r0[1]+r0[2]+r0[3];
        double A1 = r1[0]+r1[1]+r1[2]+r1[3];
        double term_lik = -A1 / ((double)BATCH_ * (double)(2*MF));
        double term_q   =  A0 / (double)BATCH_;
        out[0] = (float)(term_lik + term_q + 1.3862943611198906); // + log 4
    }
}

extern "C" void kernel_launch(void* const* d_in, const int* in_sizes, int n_in,
                              void* d_out, int out_size, void* d_ws, size_t ws_size,
                              hipStream_t stream)
{
    (void)in_sizes; (void)n_in; (void)out_size;
    const float* x       = (const float*)d_in[0];
    const float* s       = (const float*)d_in[1];
    const float* u_cat   = (const float*)d_in[2];
    const float* u_trunc = (const float*)d_in[3];
    float* out = (float*)d_out;

    float* p_ll = (float*)d_ws;             // [NB_FUSED]
    float* p_lq = p_ll + NB_FUSED;          // [NB_FUSED]
    size_t needed = (size_t)2 * NB_FUSED * sizeof(float);   // 16 KB

    if (ws_size >= needed) {
        k_bnn<<<NB_FUSED, TPB, 0, stream>>>(x, s, u_cat, u_trunc, p_ll, p_lq);
        k_fin<<<1, 256, 0, stream>>>(p_ll, p_lq, NB_FUSED, out);
    } else {
        k_mono<<<NB_MONO, 256, 0, stream>>>(x, s, u_cat, u_trunc, p_ll, p_lq);
        k_fin<<<1, 256, 0, stream>>>(p_ll, p_lq, NB_MONO, out);
    }
}

// Round 11
// 139.914 us; speedup vs baseline: 1.0878x; 1.0878x over previous
//
#include <hip/hip_runtime.h>
#include <math.h>

#define NL 5
#define KM 5
#define MF 50
#define BATCH_ 131072
#define XROW (NL + 2*MF)      /* 105 */
#define SROW (KM*(2*NL+1))    /* 55  */
#define LOG2PI_F 1.8378770664093453f

#define BPB 64                    /* batches per block, 4 lanes per batch */
#define NB_FUSED (BATCH_/BPB)     /* 2048 */
#define NB_MONO  (BATCH_/256)     /* 512  */

typedef float v2f __attribute__((ext_vector_type(2)));

__device__ __forceinline__ float rcpf_(float x)  { return __builtin_amdgcn_rcpf(x); }
__device__ __forceinline__ float sqrtf_(float x) { return __builtin_amdgcn_sqrtf(x); }
__device__ __forceinline__ float exp_(float x)   { return __expf(x); }
__device__ __forceinline__ float log_(float x)   { return __logf(x); }

// ndtr via A&S 7.1.26 erf (|eps| <= 1.5e-7)
__device__ __forceinline__ float ndtr_f(float x) {
    float z = fabsf(x) * 0.70710678f;
    float t = rcpf_(fmaf(0.3275911f, z, 1.0f));
    float poly = t*(0.254829592f + t*(-0.284496736f + t*(1.421413741f +
                 t*(-1.453152027f + t*1.061405429f))));
    float h = 0.5f * poly * exp_(-z*z);
    return x >= 0.0f ? 1.0f - h : h;
}

// ndtri via Giles' erfinv. Caller overrides exact endpoints.
__device__ __forceinline__ float ndtri_f(float p) {
    float x = fmaf(2.0f, p, -1.0f);
    float w = -log_((1.0f - x) * (1.0f + x));
    float wc = w - 2.5f;
    float pc =            2.81022636e-08f;
    pc = fmaf(pc, wc,     3.43273939e-07f);
    pc = fmaf(pc, wc,    -3.5233877e-06f);
    pc = fmaf(pc, wc,    -4.39150654e-06f);
    pc = fmaf(pc, wc,     0.00021858087f);
    pc = fmaf(pc, wc,    -0.00125372503f);
    pc = fmaf(pc, wc,    -0.00417768164f);
    pc = fmaf(pc, wc,     0.246640727f);
    pc = fmaf(pc, wc,     1.50140941f);
    float wt = sqrtf_(w) - 3.0f;
    float pt =           -0.000200214257f;
    pt = fmaf(pt, wt,     0.000100950558f);
    pt = fmaf(pt, wt,     0.00134934322f);
    pt = fmaf(pt, wt,    -0.00367342844f);
    pt = fmaf(pt, wt,     0.00573950773f);
    pt = fmaf(pt, wt,    -0.0076224613f);
    pt = fmaf(pt, wt,     0.00943887047f);
    pt = fmaf(pt, wt,     1.00167406f);
    pt = fmaf(pt, wt,     2.83297682f);
    float r = (w < 5.0f) ? pc : pt;
    return 1.41421356f * r * x;
}

// octant-reduced atan2, degree-11 odd minimax (~1e-6 rad)
__device__ __forceinline__ float atan2_f(float y, float x) {
    float ax = fabsf(x), ay = fabsf(y);
    float mx = fmaxf(ax, ay), mn = fminf(ax, ay);
    float a = mn * rcpf_(mx);
    float s = a * a;
    float r =            -0.01172120f;
    r = fmaf(r, s,        0.05265332f);
    r = fmaf(r, s,       -0.11643287f);
    r = fmaf(r, s,        0.19354346f);
    r = fmaf(r, s,       -0.33262347f);
    r = fmaf(r, s,        0.99997726f);
    r = r * a;
    r = (ay > ax)   ? (1.5707964f - r) : r;
    r = (x < 0.0f)  ? (3.1415927f - r) : r;
    return (y < 0.0f) ? -r : r;
}

// ---------- scalar forward model (fallback path) ----------
__device__ __forceinline__ float fwd_eval(float c5, float sw, float oA, float oP,
                                          const float pr[9])
{
    float ZR = sw * pr[0];
    float ZC = ZR;
    #pragma unroll
    for (int j = NL-2; j >= 0; --j) {
        float wj = sw * pr[5+j];
        float t  = sw * pr[1+j];
        float t2 = t * t, t3 = t2 * t;
        float ejR = (1.0f - t) + t3 * fmaf(-0.16666667f, t, 0.33333334f);
        float ejC = fmaf(t3, -0.33333334f, t2) - t;
        float VR = wj - ZR, VC = wj - ZC;
        float UR = wj + ZR, UC = wj + ZC;
        float WR = fmaf(ejR, VR, -ejC*VC);
        float WC = fmaf(ejR, VC,  ejC*VR);
        float NR = UR - WR, NC = UC - WC;
        float DR = UR + WR, DC = UC + WC;
        float invd = rcpf_(fmaf(DR, DR, DC*DC));
        float PR = fmaf(NR, DR,  NC*DC);
        float PC = fmaf(NC, DR, -NR*DC);
        float g  = wj * invd;
        ZR = g * (PR - PC);
        ZC = g * (PR + PC);
    }
    float absZ2 = fmaf(ZR, ZR, ZC*ZC);
    float aRes  = fmaf(0.43429448f, log_(absZ2), c5);
    float ph    = atan2_f(ZC, ZR);
    float ap    = fabsf(aRes * ph);
    float invp  = rcpf_(ap);
    float vA = (aRes - oA) * (33.333332f * fabsf(ph)   * invp);
    float vP = (ph   - oP) * (33.333332f * fabsf(aRes) * invp);
    return fmaf(-0.5f, vA*vA, fmaf(-0.5f, vP*vP, 5.1752387f - log_(ap)));
}

// ---------- packed forward model: TWO INDEPENDENT FREQUENCIES per call ------
// Components .x/.y are independent freqs -> every add/mul/fma is elementwise
// (v_pk_*_f32); only rcp/log/atan2 are per-component scalar.
__device__ __forceinline__ float fwd_eval2(v2f c5, v2f sw, v2f oA, v2f oP,
                                           const float pr[9])
{
    v2f ZR = sw * pr[0];
    v2f ZC = ZR;
    #pragma unroll
    for (int j = NL-2; j >= 0; --j) {
        v2f wj = sw * pr[5+j];
        v2f t  = sw * pr[1+j];            // <= ~0.112
        v2f t2 = t * t, t3 = t2 * t;
        v2f ejR = (1.0f - t) + t3 * (0.33333334f - 0.16666667f * t);
        v2f ejC = t2 - 0.33333334f * t3 - t;
        v2f VR = wj - ZR, VC = wj - ZC;
        v2f UR = wj + ZR, UC = wj + ZC;
        v2f WR = ejR*VR - ejC*VC;
        v2f WC = ejR*VC + ejC*VR;
        v2f NR = UR - WR, NC = UC - WC;
        v2f DR = UR + WR, DC = UC + WC;
        v2f den = DR*DR + DC*DC;
        v2f invd = {rcpf_(den.x), rcpf_(den.y)};
        v2f PR = NR*DR + NC*DC;
        v2f PC = NC*DR - NR*DC;
        v2f g  = wj * invd;
        ZR = g * (PR - PC);
        ZC = g * (PR + PC);
    }
    v2f absZ2 = ZR*ZR + ZC*ZC;
    v2f aRes = {fmaf(0.43429448f, log_(absZ2.x), c5.x),
                fmaf(0.43429448f, log_(absZ2.y), c5.y)};
    v2f ph   = {atan2_f(ZC.x, ZR.x), atan2_f(ZC.y, ZR.y)};
    v2f prod = aRes * ph;
    v2f ap   = {fabsf(prod.x), fabsf(prod.y)};
    v2f invp = {rcpf_(ap.x), rcpf_(ap.y)};
    v2f aph  = {fabsf(ph.x),   fabsf(ph.y)};
    v2f aar  = {fabsf(aRes.x), fabsf(aRes.y)};
    v2f vA = (aRes - oA) * (33.333332f * aph * invp);
    v2f vP = (ph   - oP) * (33.333332f * aar * invp);
    v2f res = (v2f){5.1752387f - log_(ap.x), 5.1752387f - log_(ap.y)}
              - 0.5f*vA*vA - 0.5f*vP*vP;
    return res.x + res.y;
}

// ---------------- fused kernel (R9 prep + packed fwd) ----------------
// prep: all 256 threads, 4 lanes/batch (2 layer-reps per lane), 64 batches
// fwd : lane i packs freq pair (i+4k, i+4k+25), k<6; uniform tail (24,49)
__global__ void __launch_bounds__(256, 4) k_bnn(
    const float* __restrict__ x, const float* __restrict__ s,
    const float* __restrict__ u_cat, const float* __restrict__ u_trunc,
    float* __restrict__ p_ll, float* __restrict__ p_lq)
{
    __shared__ float lds_pr[BPB][12];
    __shared__ float red0[4], red1[4];

    unsigned tid = threadIdx.x;
    unsigned bl = tid >> 2;               // 0..63
    unsigned i  = tid & 3;
    unsigned b  = blockIdx.x * BPB + bl;
    const float* srow = s + (size_t)b * SROW;
    float lqv = 0.0f;

    // --- batch-common (duplicated 4x per batch) ---
    float pro[KM];
    float sqsum = 0.0f;
    #pragma unroll
    for (int k = 0; k < KM; ++k) {
        float v = srow[k*11 + 10];
        pro[k] = v * v;
        sqsum += pro[k];
    }
    float isq = rcpf_(sqsum);
    #pragma unroll
    for (int k = 0; k < KM; ++k) pro[k] *= isq;
    float u = u_cat[b];
    float cum = 0.0f; int cnt = 0;
    #pragma unroll
    for (int k = 0; k < KM; ++k) { cum += pro[k]; if (u > cum) ++cnt; }
    int comp = cnt < KM-1 ? cnt : KM-1;

    // --- per-layer cells: rep 0 -> layer i, rep 1 -> layer i+4 (lane 0) ---
    float cacc[KM];
    #pragma unroll
    for (int k = 0; k < KM; ++k) cacc[k] = 0.0f;

    #pragma unroll
    for (int r = 0; r < 2; ++r) {
        unsigned layer = i + 4u*r;
        bool active = (layer < NL);
        unsigned ll_ = active ? layer : i;
        float lc[KM], sg[KM];
        #pragma unroll
        for (int k = 0; k < KM; ++k) {
            lc[k] = 4.0f * rcpf_(1.0f + exp_(-srow[k*11 + ll_]));
            float sv = srow[k*11 + 5 + ll_];
            sg[k] = fmaxf(sv, 0.0f) + log_(1.0f + exp_(-fabsf(sv)));
        }
        float ls = lc[0], ss = sg[0];
        #pragma unroll
        for (int k = 1; k < KM; ++k) {
            bool sel = (k == comp);
            ls = sel ? lc[k] : ls;
            ss = sel ? sg[k] : ss;
        }
        float invss = rcpf_(ss);
        float a  = (0.1f - ls) * invss;
        float bb = (3.9f - ls) * invss;
        float Fa = ndtr_f(a), Fb = ndtr_f(bb);
        float p  = Fa + u_trunc[(size_t)b*NL + ll_] * (Fb - Fa);
        p = fminf(fmaxf(p, 0.0f), 1.0f);
        float z = ndtri_f(p);
        if (p <= 0.0f) z = -INFINITY;
        if (p >= 1.0f) z =  INFINITY;
        float smp = fminf(fmaxf(fmaf(ss, z, ls), 0.1f), 3.9f);

        #pragma unroll
        for (int k = 0; k < KM; ++k) {
            float invs = rcpf_(sg[k]);
            float zc = (smp - lc[k]) * invs;
            float a_ = (-lc[k]) * invs;
            float b_ = (4.0f - lc[k]) * invs;
            float Z  = ndtr_f(b_) - ndtr_f(a_);   // >= ~0.29
            float v  = fmaf(-0.5f, zc*zc, -0.5f*LOG2PI_F) - log_(sg[k] * Z);
            cacc[k] += active ? v : 0.0f;
        }
        const float SQM = 7.9267442e-04f;     // sqrt(MU/2)
        const float HLN10 = 1.1512925f;       // 0.5*ln(10)
        float em  = exp_(-HLN10 * smp);       // 10^(-smp/2)
        float emi = SQM * rcpf_(em);          // SQM*10^(+smp/2)
        if (r == 0) {
            float th = x[(size_t)b*XROW + i];
            lds_pr[bl][1+i] = 2.0f * th * SQM * em;
            lds_pr[bl][5+i] = emi;
        } else if (active) {                  // lane 0: layer 4
            lds_pr[bl][0] = emi;
        }
    }
    #pragma unroll
    for (int k = 0; k < KM; ++k) {
        cacc[k] += __shfl_xor(cacc[k], 1, 4);
        cacc[k] += __shfl_xor(cacc[k], 2, 4);
    }
    {
        float mx = -INFINITY;
        float av[KM];
        #pragma unroll
        for (int k = 0; k < KM; ++k) { av[k] = log_(pro[k]) + cacc[k]; mx = fmaxf(mx, av[k]); }
        float se = 0.0f;
        #pragma unroll
        for (int k = 0; k < KM; ++k) se += exp_(av[k] - mx);
        if (i == 0) lqv = mx + log_(se);
    }
    __syncthreads();

    // --- forward phase: packed freq pairs (m, m+25), m = i+4k ---
    float pr[9];
    #pragma unroll
    for (int q = 0; q < 9; ++q) pr[q] = lds_pr[bl][q];
    const float* oAr = x + (size_t)b * XROW + NL;
    const float* oPr = oAr + MF;

    float ex0 = fmaf((float)i, 0.10204082f, -2.0f);
    v2f c5 = {5.1026102f - ex0, 5.1026102f - ex0 - 2.5510204f};
    v2f sw = {2.5066283f * exp_(1.1512925f * ex0),
              2.5066283f * exp_(1.1512925f * (ex0 + 2.5510204f))};
    float ll = 0.0f;
    #pragma unroll
    for (int k = 0; k < 6; ++k) {
        int m = (int)i + 4*k;
        v2f oA = {oAr[m], oAr[m+25]};
        v2f oP = {oPr[m], oPr[m+25]};
        ll += fwd_eval2(c5, sw, oA, oP, pr);
        c5 -= 0.40816327f;                // m += 4 (both components)
        sw *= 1.5998587f;                 // 10^(4*0.10204082/2)
    }
    // uniform tail: wave 0 covers 64 batches x packed pair (24, 49)
    if (tid < 64) {
        unsigned bt = blockIdx.x * BPB + tid;
        float prt[9];
        #pragma unroll
        for (int q = 0; q < 9; ++q) prt[q] = lds_pr[tid][q];
        const float* xa = x + (size_t)bt * XROW + NL;
        float e24 = fmaf(24.0f, 0.10204082f, -2.0f);
        float e49 = fmaf(49.0f, 0.10204082f, -2.0f);
        v2f c5t = {5.1026102f - e24, 5.1026102f - e49};
        v2f swt = {2.5066283f * exp_(1.1512925f * e24),
                   2.5066283f * exp_(1.1512925f * e49)};
        v2f oAt = {xa[24], xa[49]};
        v2f oPt = {xa[MF + 24], xa[MF + 49]};
        ll += fwd_eval2(c5t, swt, oAt, oPt, prt);
    }

    #pragma unroll
    for (int off = 32; off > 0; off >>= 1) {
        ll  += __shfl_down(ll,  off, 64);
        lqv += __shfl_down(lqv, off, 64);
    }
    if ((tid & 63) == 0) {
        red0[tid >> 6] = ll;
        red1[tid >> 6] = lqv;
    }
    __syncthreads();
    if (tid == 0) {
        p_ll[blockIdx.x] = red0[0] + red0[1] + red0[2] + red0[3];
        p_lq[blockIdx.x] = red1[0] + red1[1] + red1[2] + red1[3];
    }
}

// ---------------- fallback (tiny ws): serial per-batch ----------------
__global__ void __launch_bounds__(256) k_mono(
    const float* __restrict__ x, const float* __restrict__ s,
    const float* __restrict__ u_cat, const float* __restrict__ u_trunc,
    float* __restrict__ p_ll, float* __restrict__ p_lq)
{
    int b = blockIdx.x * 256 + threadIdx.x;
    const float* srow = s + (size_t)b * SROW;
    float loc[KM][NL], sig[KM][NL], pro[KM];
    float sqsum = 0.0f;
    #pragma unroll
    for (int k = 0; k < KM; ++k) { float v = srow[k*11+10]; pro[k] = v*v; sqsum += pro[k]; }
    float isq = rcpf_(sqsum);
    #pragma unroll
    for (int k = 0; k < KM; ++k) pro[k] *= isq;
    #pragma unroll
    for (int k = 0; k < KM; ++k)
        #pragma unroll
        for (int i = 0; i < NL; ++i) {
            loc[k][i] = 4.0f * rcpf_(1.0f + exp_(-srow[k*11+i]));
            float v = srow[k*11+5+i];
            sig[k][i] = fmaxf(v, 0.0f) + log_(1.0f + exp_(-fabsf(v)));
        }
    float u = u_cat[b];
    float cum = 0.0f; int cnt = 0;
    #pragma unroll
    for (int k = 0; k < KM; ++k) { cum += pro[k]; if (u > cum) ++cnt; }
    int comp = cnt < KM-1 ? cnt : KM-1;
    float ls[NL], ss[NL];
    #pragma unroll
    for (int i = 0; i < NL; ++i) { ls[i] = loc[0][i]; ss[i] = sig[0][i]; }
    #pragma unroll
    for (int k = 1; k < KM; ++k) {
        bool sel = (k == comp);
        #pragma unroll
        for (int i = 0; i < NL; ++i) {
            ls[i] = sel ? loc[k][i] : ls[i];
            ss[i] = sel ? sig[k][i] : ss[i];
        }
    }
    float smp[NL];
    #pragma unroll
    for (int i = 0; i < NL; ++i) {
        float invss = rcpf_(ss[i]);
        float a  = (0.1f - ls[i]) * invss;
        float bb = (3.9f - ls[i]) * invss;
        float Fa = ndtr_f(a), Fb = ndtr_f(bb);
        float p  = Fa + u_trunc[(size_t)b*NL + i] * (Fb - Fa);
        p = fminf(fmaxf(p, 0.0f), 1.0f);
        float z  = ndtri_f(p);
        if (p <= 0.0f) z = -INFINITY;
        if (p >= 1.0f) z =  INFINITY;
        smp[i] = fminf(fmaxf(fmaf(ss[i], z, ls[i]), 0.1f), 3.9f);
    }
    float vals[KM]; float mx = -INFINITY;
    #pragma unroll
    for (int k = 0; k < KM; ++k) {
        float av = log_(pro[k]);
        #pragma unroll
        for (int i = 0; i < NL; ++i) {
            float l = loc[k][i], sgv = sig[k][i];
            float invs = rcpf_(sgv);
            float zc = (smp[i] - l) * invs;
            float a_ = (-l) * invs;
            float b_ = (4.0f - l) * invs;
            float Z  = ndtr_f(b_) - ndtr_f(a_);
            av += fmaf(-0.5f, zc*zc, -0.5f*LOG2PI_F) - log_(sgv * Z);
        }
        vals[k] = av; mx = fmaxf(mx, av);
    }
    float se = 0.0f;
    #pragma unroll
    for (int k = 0; k < KM; ++k) se += exp_(vals[k] - mx);
    float lq = mx + log_(se);
    const float SQM = 7.9267442e-04f;
    const float HLN10 = 1.1512925f;
    float pr[9];
    pr[0] = SQM * exp_(HLN10 * smp[NL-1]);
    #pragma unroll
    for (int j = 0; j < NL-1; ++j) {
        float em = exp_(-HLN10 * smp[j]);
        float th = x[(size_t)b*XROW + j];
        pr[1+j] = 2.0f * th * SQM * em;
        pr[5+j] = SQM * rcpf_(em);
    }
    const float* xrow = x + (size_t)b * XROW;
    float ll = 0.0f;
    for (int m = 0; m < MF; ++m) {
        float ex = fmaf((float)m, 0.10204082f, -2.0f);
        float sw = 2.5066283f * exp_(1.1512925f * ex);
        ll += fwd_eval(5.1026102f - ex, sw, xrow[NL + m], xrow[NL + MF + m], pr);
    }

    __shared__ float red0[4], red1[4];
    #pragma unroll
    for (int off = 32; off > 0; off >>= 1) {
        ll += __shfl_down(ll, off, 64);
        lq += __shfl_down(lq, off, 64);
    }
    if ((threadIdx.x & 63) == 0) { red0[threadIdx.x>>6] = ll; red1[threadIdx.x>>6] = lq; }
    __syncthreads();
    if (threadIdx.x == 0) {
        p_ll[blockIdx.x] = red0[0]+red0[1]+red0[2]+red0[3];
        p_lq[blockIdx.x] = red1[0]+red1[1]+red1[2]+red1[3];
    }
}

// ---------------- final reduction ----------------
__global__ void __launch_bounds__(256) k_fin(
    const float* __restrict__ p_ll, const float* __restrict__ p_lq, int n,
    float* __restrict__ out)
{
    int tid = threadIdx.x;
    double a1 = 0.0, a0 = 0.0;
    for (int j = tid; j < n; j += 256) {
        a1 += (double)p_ll[j];
        a0 += (double)p_lq[j];
    }
    #pragma unroll
    for (int off = 32; off > 0; off >>= 1) {
        a0 += __shfl_down(a0, off, 64);
        a1 += __shfl_down(a1, off, 64);
    }
    __shared__ double r0[4], r1[4];
    if ((tid & 63) == 0) { r0[tid >> 6] = a0; r1[tid >> 6] = a1; }
    __syncthreads();
    if (tid == 0) {
        double A0 = r0[0]+r0[1]+r0[2]+r0[3];
        double A1 = r1[0]+r1[1]+r1[2]+r1[3];
        double term_lik = -A1 / ((double)BATCH_ * (double)(2*MF));
        double term_q   =  A0 / (double)BATCH_;
        out[0] = (float)(term_lik + term_q + 1.3862943611198906); // + log 4
    }
}

extern "C" void kernel_launch(void* const* d_in, const int* in_sizes, int n_in,
                              void* d_out, int out_size, void* d_ws, size_t ws_size,
                              hipStream_t stream)
{
    (void)in_sizes; (void)n_in; (void)out_size;
    const float* x       = (const float*)d_in[0];
    const float* s       = (const float*)d_in[1];
    const float* u_cat   = (const float*)d_in[2];
    const float* u_trunc = (const float*)d_in[3];
    float* out = (float*)d_out;

    float* p_ll = (float*)d_ws;             // [NB_FUSED]
    float* p_lq = p_ll + NB_FUSED;          // [NB_FUSED]
    size_t needed = (size_t)2 * NB_FUSED * sizeof(float);   // 16 KB

    if (ws_size >= needed) {
        k_bnn<<<NB_FUSED, 256, 0, stream>>>(x, s, u_cat, u_trunc, p_ll, p_lq);
        k_fin<<<1, 256, 0, stream>>>(p_ll, p_lq, NB_FUSED, out);
    } else {
        k_mono<<<NB_MONO, 256, 0, stream>>>(x, s, u_cat, u_trunc, p_ll, p_lq);
        k_fin<<<1, 256, 0, stream>>>(p_ll, p_lq, NB_MONO, out);
    }
}